// Round 1
// baseline (257.359 us; speedup 1.0000x reference)
//
#include <hip/hip_runtime.h>
#include <hip/hip_bf16.h>

#define BATCH    256
#define NU       300
#define LIN      608
#define FILT     19
#define LCONV    588   // only first 84*7 conv positions feed the pool
#define LPOOL    84
#define POOL     7
#define HID      100
#define NCLS     50
#define EPS      1e-5f
#define UPB      3     // units per block in k_conv

// ---------------------------------------------------------------------------
// Kernel 1: conv(4->300, k=19) + bias + BN + exp + maxpool(7)
//   exp(bn(.)) is monotone (scale>0) -> pool raw conv, then one bn+exp.
//   Output layout transposed: ypool[u][p][b]  (coalesced reads in k_mlp)
// ---------------------------------------------------------------------------
__global__ __launch_bounds__(256, 4)
void k_conv(const float* __restrict__ x, const float* __restrict__ w1,
            const float* __restrict__ b1, const float* __restrict__ g1,
            const float* __restrict__ be1, const float* __restrict__ m1,
            const float* __restrict__ v1, float* __restrict__ ypool)
{
    __shared__ __align__(16) float xs[4 * LIN];     // 9728 B
    __shared__ float wsh[UPB * 4 * FILT];           // 912 B
    __shared__ float s_sh[UPB], c_sh[UPB];

    const int tid = threadIdx.x;
    const int u0  = blockIdx.x * UPB;
    const int b   = blockIdx.y;

    // stage x[b] (4*608 floats) as float4
    {
        const float4* xg = (const float4*)(x + (size_t)b * 4 * LIN);
        float4* xd = (float4*)xs;
        for (int i = tid; i < (4 * LIN) / 4; i += 256) xd[i] = xg[i];
    }
    // stage weights for UPB units
    for (int i = tid; i < UPB * 4 * FILT; i += 256)
        wsh[i] = w1[u0 * 4 * FILT + i];
    // folded BN constants: y_bn = conv*s + c
    if (tid < UPB) {
        int u = u0 + tid;
        float s = g1[u] * rsqrtf(v1[u] + EPS);
        s_sh[tid] = s;
        c_sh[tid] = (b1[u] - m1[u]) * s + be1[u];
    }
    __syncthreads();

    if (tid < UPB * LPOOL) {
        const int ul = tid / LPOOL;
        const int p  = tid - ul * LPOOL;
        const int base = p * POOL;
        const float* wp = &wsh[ul * 4 * FILT];

        float acc[POOL];
#pragma unroll
        for (int j = 0; j < POOL; ++j) acc[j] = 0.f;

#pragma unroll
        for (int c = 0; c < 4; ++c) {
            float xr[POOL + FILT - 1];   // 25-float sliding window
#pragma unroll
            for (int i = 0; i < POOL + FILT - 1; ++i)
                xr[i] = xs[c * LIN + base + i];
#pragma unroll
            for (int k = 0; k < FILT; ++k) {
                const float w = wp[c * FILT + k];
#pragma unroll
                for (int j = 0; j < POOL; ++j)
                    acc[j] = fmaf(xr[k + j], w, acc[j]);
            }
        }
        float m = acc[0];
#pragma unroll
        for (int j = 1; j < POOL; ++j) m = fmaxf(m, acc[j]);

        const float out = __expf(fmaf(m, s_sh[ul], c_sh[ul]));
        ypool[((size_t)(u0 + ul) * LPOOL + p) * BATCH + b] = out;
    }
}

// ---------------------------------------------------------------------------
// Kernel 2: per-unit MLP 84 -> 100 (+BN+ReLU) -> 1 (+BN+ReLU)
//   block = 256 threads (thread = batch), grid = 300 units
//   w2[u] staged in LDS (33.6 KB), y row in 84 registers
//   zbuf layout [u][b]
// ---------------------------------------------------------------------------
__global__ __launch_bounds__(256, 2)
void k_mlp(const float* __restrict__ ypool, const float* __restrict__ w2,
           const float* __restrict__ b2, const float* __restrict__ g2,
           const float* __restrict__ be2, const float* __restrict__ m2,
           const float* __restrict__ v2, const float* __restrict__ w3,
           const float* __restrict__ b3, const float* __restrict__ g3,
           const float* __restrict__ be3, const float* __restrict__ m3,
           const float* __restrict__ v3, float* __restrict__ zbuf)
{
    __shared__ __align__(16) float w2s[HID * LPOOL];   // 33600 B
    __shared__ float s2s[HID], c2s[HID], w3s[HID];

    const int u = blockIdx.x;
    const int b = threadIdx.x;

    {
        const float4* src = (const float4*)(w2 + (size_t)u * HID * LPOOL);
        float4* dst = (float4*)w2s;
        for (int i = threadIdx.x; i < (HID * LPOOL) / 4; i += 256) dst[i] = src[i];
    }
    if (threadIdx.x < HID) {
        const int o = threadIdx.x;
        const float s = g2[u * HID + o] * rsqrtf(v2[u * HID + o] + EPS);
        s2s[o] = s;
        c2s[o] = (b2[u * HID + o] - m2[u * HID + o]) * s + be2[u * HID + o];
        w3s[o] = w3[u * HID + o];
    }
    __syncthreads();

    float yreg[LPOOL];
    const float* yp = ypool + (size_t)u * LPOOL * BATCH + b;
#pragma unroll
    for (int f = 0; f < LPOOL; ++f) yreg[f] = yp[f * BATCH];

    float z = 0.f;
#pragma unroll 2
    for (int o = 0; o < HID; ++o) {
        const float4* wr = (const float4*)&w2s[o * LPOOL];
        float h = 0.f;
#pragma unroll
        for (int q = 0; q < LPOOL / 4; ++q) {
            const float4 wv = wr[q];
            h = fmaf(yreg[4 * q + 0], wv.x, h);
            h = fmaf(yreg[4 * q + 1], wv.y, h);
            h = fmaf(yreg[4 * q + 2], wv.z, h);
            h = fmaf(yreg[4 * q + 3], wv.w, h);
        }
        h = fmaxf(fmaf(h, s2s[o], c2s[o]), 0.f);
        z = fmaf(h, w3s[o], z);
    }

    const float s3 = g3[u] * rsqrtf(v3[u] + EPS);
    const float c3 = (b3[u] - m3[u]) * s3 + be3[u];
    z = fmaxf(fmaf(z, s3, c3), 0.f);
    zbuf[(size_t)u * BATCH + b] = z;
}

// ---------------------------------------------------------------------------
// Kernel 3: final linear 300 -> 50.  grid = 50 (one block per class),
//   thread = batch; wf reads are wave-uniform (scalar path).
// ---------------------------------------------------------------------------
__global__ __launch_bounds__(256, 1)
void k_final(const float* __restrict__ zbuf, const float* __restrict__ wf,
             const float* __restrict__ bf, float* __restrict__ out)
{
    const int n = blockIdx.x;
    const int b = threadIdx.x;
    float acc = 0.f;
#pragma unroll 4
    for (int u = 0; u < NU; ++u)
        acc = fmaf(zbuf[(size_t)u * BATCH + b], wf[n * NU + u], acc);
    out[(size_t)b * NCLS + n] = acc + bf[n];
}

extern "C" void kernel_launch(void* const* d_in, const int* in_sizes, int n_in,
                              void* d_out, int out_size, void* d_ws, size_t ws_size,
                              hipStream_t stream)
{
    const float* x   = (const float*)d_in[0];
    const float* w1  = (const float*)d_in[1];
    const float* b1  = (const float*)d_in[2];
    const float* g1  = (const float*)d_in[3];
    const float* be1 = (const float*)d_in[4];
    const float* m1  = (const float*)d_in[5];
    const float* v1  = (const float*)d_in[6];
    const float* w2  = (const float*)d_in[7];
    const float* b2  = (const float*)d_in[8];
    const float* g2  = (const float*)d_in[9];
    const float* be2 = (const float*)d_in[10];
    const float* m2  = (const float*)d_in[11];
    const float* v2  = (const float*)d_in[12];
    const float* w3  = (const float*)d_in[13];
    const float* b3  = (const float*)d_in[14];
    const float* g3  = (const float*)d_in[15];
    const float* be3 = (const float*)d_in[16];
    const float* m3  = (const float*)d_in[17];
    const float* v3  = (const float*)d_in[18];
    const float* wf  = (const float*)d_in[19];
    const float* bf  = (const float*)d_in[20];

    float* ypool = (float*)d_ws;                                // 300*84*256 fp32 = 25.8 MB
    float* zbuf  = ypool + (size_t)NU * LPOOL * BATCH;          // 300*256 fp32

    dim3 g1d(NU / UPB, BATCH);
    k_conv<<<g1d, 256, 0, stream>>>(x, w1, b1, g1, be1, m1, v1, ypool);
    k_mlp<<<NU, 256, 0, stream>>>(ypool, w2, b2, g2, be2, m2, v2,
                                  w3, b3, g3, be3, m3, v3, zbuf);
    k_final<<<NCLS, 256, 0, stream>>>(zbuf, wf, bf, (float*)d_out);
}